// Round 1
// baseline (256.778 us; speedup 1.0000x reference)
//
#include <hip/hip_runtime.h>
#include <hip/hip_bf16.h>

#define EPS_THETA 1e-6f

__global__ __launch_bounds__(256) void se3_compose_kernel(
    const float* __restrict__ xi,
    const float* __restrict__ poses,
    float* __restrict__ out,
    int n)
{
    int i = blockIdx.x * blockDim.x + threadIdx.x;
    if (i >= n) return;

    // ---- load xi[i, 0:6] as 3x float2 (24*i bytes is always 8-aligned) ----
    const float2* x2 = (const float2*)(xi + 6ll * i);
    float2 a = x2[0];  // t0, t1
    float2 b = x2[1];  // t2, w0
    float2 c2 = x2[2]; // w1, w2
    float t0 = a.x, t1 = a.y, t2 = b.x;
    float w0 = b.y, w1 = c2.x, w2 = c2.y;

    // ---- Rodrigues / small-angle, branchless select ----
    float theta2 = w0 * w0 + w1 * w1 + w2 * w2;
    float theta  = sqrtf(theta2);
    bool  small_ = theta < EPS_THETA;

    float inv = small_ ? 1.0f : (1.0f / theta);
    float k0 = w0 * inv, k1 = w1 * inv, k2 = w2 * inv;

    float s = small_ ? 1.0f : sinf(theta);
    float c = small_ ? 0.0f : (1.0f - cosf(theta));

    // R = I + s*K + c*(k k^T - I)   (|k| = 1 in the non-small path)
    float R00 = 1.0f + c * (k0 * k0 - 1.0f);
    float R01 = c * k0 * k1 - s * k2;
    float R02 = c * k0 * k2 + s * k1;
    float R10 = c * k0 * k1 + s * k2;
    float R11 = 1.0f + c * (k1 * k1 - 1.0f);
    float R12 = c * k1 * k2 - s * k0;
    float R20 = c * k0 * k2 - s * k1;
    float R21 = c * k1 * k2 + s * k0;
    float R22 = 1.0f + c * (k2 * k2 - 1.0f);

    // ---- load pose rows (4x float4, 64B contiguous per thread) ----
    const float4* P = (const float4*)(poses + 16ll * i);
    float4 p0 = P[0];
    float4 p1 = P[1];
    float4 p2 = P[2];
    float4 p3 = P[3];

    // ---- out rows 0..2: R[r][:]*P + t[r]*p3 ; row 3 = p3 (T bottom row = e3) ----
    float4* O = (float4*)(out + 16ll * i);

    float4 o0, o1, o2;
    o0.x = R00 * p0.x + R01 * p1.x + R02 * p2.x + t0 * p3.x;
    o0.y = R00 * p0.y + R01 * p1.y + R02 * p2.y + t0 * p3.y;
    o0.z = R00 * p0.z + R01 * p1.z + R02 * p2.z + t0 * p3.z;
    o0.w = R00 * p0.w + R01 * p1.w + R02 * p2.w + t0 * p3.w;

    o1.x = R10 * p0.x + R11 * p1.x + R12 * p2.x + t1 * p3.x;
    o1.y = R10 * p0.y + R11 * p1.y + R12 * p2.y + t1 * p3.y;
    o1.z = R10 * p0.z + R11 * p1.z + R12 * p2.z + t1 * p3.z;
    o1.w = R10 * p0.w + R11 * p1.w + R12 * p2.w + t1 * p3.w;

    o2.x = R20 * p0.x + R21 * p1.x + R22 * p2.x + t2 * p3.x;
    o2.y = R20 * p0.y + R21 * p1.y + R22 * p2.y + t2 * p3.y;
    o2.z = R20 * p0.z + R21 * p1.z + R22 * p2.z + t2 * p3.z;
    o2.w = R20 * p0.w + R21 * p1.w + R22 * p2.w + t2 * p3.w;

    O[0] = o0;
    O[1] = o1;
    O[2] = o2;
    O[3] = p3;
}

extern "C" void kernel_launch(void* const* d_in, const int* in_sizes, int n_in,
                              void* d_out, int out_size, void* d_ws, size_t ws_size,
                              hipStream_t stream) {
    const float* xi    = (const float*)d_in[0];
    const float* poses = (const float*)d_in[1];
    float*       out   = (float*)d_out;

    int n = in_sizes[0] / 6;  // N = 2,000,000

    const int block = 256;
    const int grid  = (n + block - 1) / block;
    se3_compose_kernel<<<grid, block, 0, stream>>>(xi, poses, out, n);
}

// Round 2
// 246.266 us; speedup vs baseline: 1.0427x; 1.0427x over previous
//
#include <hip/hip_runtime.h>
#include <hip/hip_bf16.h>

#define EPS_THETA 1e-6f

__device__ __forceinline__ float4 shfl4(float4 v, int src) {
    float4 r;
    r.x = __shfl(v.x, src, 4);
    r.y = __shfl(v.y, src, 4);
    r.z = __shfl(v.z, src, 4);
    r.w = __shfl(v.w, src, 4);
    return r;
}

// 4 lanes per pose: lane j -> pose p = j>>2, row r = j&3.
// Pose loads + output stores are lane-consecutive float4 (fully coalesced).
__global__ __launch_bounds__(256) void se3_compose_kernel(
    const float* __restrict__ xi,
    const float4* __restrict__ poses4,   // flat float4 view, length 4*n
    float4* __restrict__ out4,           // flat float4 view, length 4*n
    int n4)                              // = 4*n
{
    int i = blockIdx.x * blockDim.x + threadIdx.x;
    if (i >= n4) return;

    int p = i >> 2;   // pose index
    int r = i & 3;    // my row of the pose / output

    // ---- load xi[p, 0:6] (quad-redundant; same cache lines within quad) ----
    const float2* x2 = (const float2*)(xi + 6ll * p);
    float2 a  = x2[0];  // t0, t1
    float2 b  = x2[1];  // t2, w0
    float2 cc = x2[2];  // w1, w2
    float t0 = a.x, t1 = a.y, t2 = b.x;
    float w0 = b.y, w1 = cc.x, w2 = cc.y;

    // ---- my pose row: perfectly coalesced float4 ----
    float4 pr = poses4[i];

    // ---- Rodrigues / small-angle, branchless ----
    float theta2 = w0 * w0 + w1 * w1 + w2 * w2;
    float theta  = sqrtf(theta2);
    bool  small_ = theta < EPS_THETA;

    float inv = small_ ? 1.0f : (1.0f / theta);
    float k0 = w0 * inv, k1 = w1 * inv, k2 = w2 * inv;

    float s = small_ ? 1.0f : sinf(theta);
    float c = small_ ? 0.0f : (1.0f - cosf(theta));

    // R = I + s*K + c*(k k^T - I)
    float R00 = 1.0f + c * (k0 * k0 - 1.0f);
    float R01 = c * k0 * k1 - s * k2;
    float R02 = c * k0 * k2 + s * k1;
    float R10 = c * k0 * k1 + s * k2;
    float R11 = 1.0f + c * (k1 * k1 - 1.0f);
    float R12 = c * k1 * k2 - s * k0;
    float R20 = c * k0 * k2 - s * k1;
    float R21 = c * k1 * k2 + s * k0;
    float R22 = 1.0f + c * (k2 * k2 - 1.0f);

    // ---- row coefficients for my output row: out_r = c0*P0 + c1*P1 + c2*P2 + c3*P3 ----
    float c0 = (r == 0) ? R00 : (r == 1) ? R10 : (r == 2) ? R20 : 0.0f;
    float c1 = (r == 0) ? R01 : (r == 1) ? R11 : (r == 2) ? R21 : 0.0f;
    float c2 = (r == 0) ? R02 : (r == 1) ? R12 : (r == 2) ? R22 : 0.0f;
    float c3 = (r == 0) ? t0  : (r == 1) ? t1  : (r == 2) ? t2  : 1.0f;

    // ---- gather all 4 pose rows from the quad ----
    float4 P0 = shfl4(pr, 0);
    float4 P1 = shfl4(pr, 1);
    float4 P2 = shfl4(pr, 2);
    float4 P3 = shfl4(pr, 3);

    float4 o;
    o.x = c0 * P0.x + c1 * P1.x + c2 * P2.x + c3 * P3.x;
    o.y = c0 * P0.y + c1 * P1.y + c2 * P2.y + c3 * P3.y;
    o.z = c0 * P0.z + c1 * P1.z + c2 * P2.z + c3 * P3.z;
    o.w = c0 * P0.w + c1 * P1.w + c2 * P2.w + c3 * P3.w;

    out4[i] = o;   // perfectly coalesced
}

extern "C" void kernel_launch(void* const* d_in, const int* in_sizes, int n_in,
                              void* d_out, int out_size, void* d_ws, size_t ws_size,
                              hipStream_t stream) {
    const float*  xi     = (const float*)d_in[0];
    const float4* poses4 = (const float4*)d_in[1];
    float4*       out4   = (float4*)d_out;

    int n  = in_sizes[0] / 6;  // N = 2,000,000
    int n4 = 4 * n;

    const int block = 256;
    const int grid  = (n4 + block - 1) / block;
    se3_compose_kernel<<<grid, block, 0, stream>>>(xi, poses4, out4, n4);
}